// Round 5
// baseline (141.913 us; speedup 1.0000x reference)
//
#include <hip/hip_runtime.h>
#include <hip/hip_bf16.h>

typedef float f32x4 __attribute__((ext_vector_type(4)));
typedef short bf16x8 __attribute__((ext_vector_type(8)));
typedef float float4v __attribute__((ext_vector_type(4)));

#define H1_STRIDE 40    // shorts; 32 + 8 pad
#define W1T_K 576
#define W2T_OFF (48 * 576)

__device__ __forceinline__ short f2bf(float f) {
  __bf16 b = (__bf16)f;
  return __builtin_bit_cast(short, b);
}
__device__ __forceinline__ uint pack2(float a, float b) {
  return (uint)(unsigned short)f2bf(a) | ((uint)(unsigned short)f2bf(b) << 16);
}
__device__ __forceinline__ float fast_sigmoid(float x) {
  return __builtin_amdgcn_rcpf(1.f + __expf(-x));
}
__device__ __forceinline__ float fast_tanh(float x) {
  float e = __expf(2.f * x);
  return 1.f - 2.f * __builtin_amdgcn_rcpf(e + 1.f);  // exact identity; saturates at +-1
}

// ---- prep: bf16 weight layouts in d_ws ----
// ws[0 .. 48*576)        : W1bT[n][k] = (n<32 ? W1[k][n] : n==32 ? Wr[k] : 0)   [K-contig]
// ws[48*576 .. +32*1024) : W2T[n][k] = W2[k][n]                                  [K-contig]
__global__ __launch_bounds__(256) void prep_weights(
    const float* __restrict__ W1, const float* __restrict__ W2,
    const float* __restrict__ Wr, short* __restrict__ ws)
{
  int i = blockIdx.x * 256 + threadIdx.x;
  if (i < 48 * 576) {
    int n = i / 576;
    int k = i - n * 576;
    float v = 0.f;
    if (n < 32) v = W1[k * 32 + n];
    else if (n == 32) v = Wr[k];
    ws[i] = f2bf(v);
  } else {
    int j = i - 48 * 576;
    if (j < 32 * 1024) {
      int n = j >> 5;
      int k = j & 31;
      ws[W2T_OFF + j] = f2bf(W2[k * 1024 + n]);
    }
  }
}

// Wave-PAIR decomposition: block = 4 waves = 2 pairs, 32 rows/block, grid 2048,
// 8192 waves total -> 32 waves/CU if VGPR<=64. Within a pair (rows m0..m0+15):
//   wave ks=0: fc1 k-steps 0..8,  fc2 col-tiles 0..7
//   wave ks=1: fc1 k-steps 9..17, fc2 col-tiles 8..15
// fc1 partials exchanged via LDS with raw lgkmcnt+s_barrier (keeps prev_c
// prefetch in flight across the barrier -- no vmcnt(0) drain).
// All MFMAs transposed (weights=A, activations=B): lane owns batch row m0+ln,
// 4 consecutive out cols per acc reg -> dwordx4 pc loads / out stores.
__global__ __launch_bounds__(256, 8) void fclstm_main(
    const float* __restrict__ prev_h, const float* __restrict__ prev_c,
    const float* __restrict__ action, const float* __restrict__ dynamics,
    const float* __restrict__ b1, const float* __restrict__ b2,
    const float* __restrict__ Wr, const float* __restrict__ br,
    const short* __restrict__ wsw,
    float* __restrict__ out_h, float* __restrict__ out_c, float* __restrict__ out_r)
{
  __shared__ f32x4 accx[4][3][64];        // 12,288 B : fc1 partial exchange (lane-major: conflict-free)
  __shared__ short h1T[4][16 * H1_STRIDE]; //  5,120 B : per-wave h1 transpose buffer
  __shared__ float rlds[2][16];            //    128 B : reward partial (ks=1 -> ks=0)

  const int t    = threadIdx.x;
  const int wid  = t >> 6;
  const int lane = t & 63;
  const int lg   = lane >> 4;
  const int ln   = lane & 15;
  const int p    = wid >> 1;      // pair index 0/1
  const int ks   = wid & 1;       // k-half / col-half
  const int r0   = blockIdx.x * 32;
  const int m0   = p << 4;
  const int rowA = r0 + m0 + ln;  // THE batch row this lane owns
  const int kb   = 8 * lg;

  // ---- prev_c preload, first 4 of this wave's 8 col-tiles (hides under fc1)
  const float* pcp = prev_c + (size_t)rowA * 256 + ks * 128 + 4 * lg;
  float4v pcA[4], pcB[4];
  #pragma unroll
  for (int q = 0; q < 4; ++q) pcA[q] = *(const float4v*)(pcp + q * 16);

  // ---- fc1 partial: this wave's 9 k-steps ----
  f32x4 acc0 = {0.f,0.f,0.f,0.f};  // fc1 cols  0..15
  f32x4 acc1 = {0.f,0.f,0.f,0.f};  // fc1 cols 16..31
  f32x4 acc2 = {0.f,0.f,0.f,0.f};  // fc1 cols 32..47 (col 32 = x . Wr[0:576])

  const float* dynp = dynamics + rowA * 256 + kb;
  const float* actp = action   + rowA * 64  + kb;
  const float* hp   = prev_h   + rowA * 256 + kb;
  const short* w1f  = wsw + ln * W1T_K + kb;

  auto fc1_step = [&](int j, const float* src) {
    float4v v0 = *(const float4v*)src;
    float4v v1 = *(const float4v*)(src + 4);
    bf16x8 a;
    a[0] = f2bf(v0.x); a[1] = f2bf(v0.y); a[2] = f2bf(v0.z); a[3] = f2bf(v0.w);
    a[4] = f2bf(v1.x); a[5] = f2bf(v1.y); a[6] = f2bf(v1.z); a[7] = f2bf(v1.w);
    bf16x8 bA = *(const bf16x8*)(w1f + 32 * j);
    bf16x8 bB = *(const bf16x8*)(w1f + 16 * W1T_K + 32 * j);
    bf16x8 bC = *(const bf16x8*)(w1f + 32 * W1T_K + 32 * j);
    acc0 = __builtin_amdgcn_mfma_f32_16x16x32_bf16(bA, a, acc0, 0, 0, 0);
    acc1 = __builtin_amdgcn_mfma_f32_16x16x32_bf16(bB, a, acc1, 0, 0, 0);
    acc2 = __builtin_amdgcn_mfma_f32_16x16x32_bf16(bC, a, acc2, 0, 0, 0);
  };

  if (ks == 0) {
    #pragma unroll
    for (int j = 0; j < 9; ++j)
      fc1_step(j, (j < 8) ? dynp + 32 * j : actp + 32 * j - 256);
  } else {
    #pragma unroll
    for (int j = 9; j < 18; ++j)
      fc1_step(j, (j < 10) ? actp + 32 * j - 256 : hp + 32 * j - 320);
  }

  // ---- exchange fc1 partials with the partner wave (raw barrier: no vmcnt drain)
  accx[wid][0][lane] = acc0;
  accx[wid][1][lane] = acc1;
  accx[wid][2][lane] = acc2;
  asm volatile("s_waitcnt lgkmcnt(0)" ::: "memory");
  __builtin_amdgcn_s_barrier();
  __builtin_amdgcn_sched_barrier(0);
  {
    const int pw = wid ^ 1;
    acc0 += accx[pw][0][lane];
    acc1 += accx[pw][1][lane];
    acc2 += accx[pw][2][lane];
  }

  // prev_c batch 1 (this wave's tiles 4..7) — issue now, hides under pack+fc2 start
  #pragma unroll
  for (int q = 0; q < 4; ++q) pcB[q] = *(const float4v*)(pcp + 64 + q * 16);

  // ---- h1 = tanh(.+b1); wave-local LDS transpose to build the fc2 B-frag
  {
    float4v b1lo = *(const float4v*)&b1[4 * lg];
    float4v b1hi = *(const float4v*)&b1[16 + 4 * lg];
    uint2 wlo, whi;
    wlo.x = pack2(fast_tanh(acc0[0] + b1lo.x), fast_tanh(acc0[1] + b1lo.y));
    wlo.y = pack2(fast_tanh(acc0[2] + b1lo.z), fast_tanh(acc0[3] + b1lo.w));
    whi.x = pack2(fast_tanh(acc1[0] + b1hi.x), fast_tanh(acc1[1] + b1hi.y));
    whi.y = pack2(fast_tanh(acc1[2] + b1hi.z), fast_tanh(acc1[3] + b1hi.w));
    short* hrow = &h1T[wid][ln * H1_STRIDE];
    *(uint2*)(hrow + 4 * lg)      = wlo;
    *(uint2*)(hrow + 16 + 4 * lg) = whi;
  }
  asm volatile("s_waitcnt lgkmcnt(0)" ::: "memory");
  __builtin_amdgcn_sched_barrier(0);
  bf16x8 af2 = *(const bf16x8*)(&h1T[wid][ln * H1_STRIDE] + 8 * lg);

  // ---- fc2 + LSTM elementwise + reward: this wave's 8 col-tiles ----
  float racc = 0.f;
  const float br0 = br[0];
  const short* w2t = wsw + W2T_OFF;
  const size_t orow = (size_t)rowA * 256;

  auto fc2_tile = [&](int nt, float4v pc) {
    const int c4 = nt * 16 + 4 * lg;                      // 4 consecutive out cols
    const short* aw = w2t + (nt * 16 + ln) * 32 + 8 * lg; // W2T rows as A-operand
    bf16x8 wi = *(const bf16x8*)(aw);
    bf16x8 wf = *(const bf16x8*)(aw + 256 * 32);
    bf16x8 wc = *(const bf16x8*)(aw + 512 * 32);
    bf16x8 wo = *(const bf16x8*)(aw + 768 * 32);
    f32x4 gi = {0.f,0.f,0.f,0.f}, gf = {0.f,0.f,0.f,0.f};
    f32x4 gc = {0.f,0.f,0.f,0.f}, go = {0.f,0.f,0.f,0.f};
    gi = __builtin_amdgcn_mfma_f32_16x16x32_bf16(wi, af2, gi, 0, 0, 0);
    gf = __builtin_amdgcn_mfma_f32_16x16x32_bf16(wf, af2, gf, 0, 0, 0);
    gc = __builtin_amdgcn_mfma_f32_16x16x32_bf16(wc, af2, gc, 0, 0, 0);
    go = __builtin_amdgcn_mfma_f32_16x16x32_bf16(wo, af2, go, 0, 0, 0);
    float4v b2i = *(const float4v*)&b2[c4];
    float4v b2f = *(const float4v*)&b2[256 + c4];
    float4v b2c = *(const float4v*)&b2[512 + c4];
    float4v b2o = *(const float4v*)&b2[768 + c4];
    float4v wrv = *(const float4v*)&Wr[576 + c4];
    float4v nh, nc2;
    #pragma unroll
    for (int r = 0; r < 4; ++r) {
      float iv  = fast_sigmoid(gi[r] + b2i[r]);
      float fv  = fast_sigmoid(gf[r] + b2f[r]);
      float cv  = fast_tanh(gc[r] + b2c[r]);
      float ov  = fast_sigmoid(go[r] + b2o[r]);
      float ncv = fv * pc[r] + iv * cv;
      float nhv = ov * fast_tanh(ncv);
      nh[r]  = nhv;
      nc2[r] = ncv;
      racc += nhv * wrv[r];
    }
    __builtin_nontemporal_store(nh,  (float4v*)(out_h + orow + c4));
    __builtin_nontemporal_store(nc2, (float4v*)(out_c + orow + c4));
  };

  #pragma unroll
  for (int q = 0; q < 4; ++q) fc2_tile(ks * 8 + q, pcA[q]);
  #pragma unroll
  for (int q = 0; q < 4; ++q) fc2_tile(ks * 8 + 4 + q, pcB[q]);

  // ---- reward: combine lg groups, then the two waves of the pair ----
  racc += __shfl_xor(racc, 16, 64);
  racc += __shfl_xor(racc, 32, 64);
  if (ks == 1 && lane < 16) rlds[p][lane] = racc;
  asm volatile("s_waitcnt lgkmcnt(0)" ::: "memory");
  __builtin_amdgcn_s_barrier();
  __builtin_amdgcn_sched_barrier(0);
  if (ks == 0 && lg == 0) {
    float s = acc2[0] + racc + rlds[p][ln] + br0;
    __builtin_nontemporal_store(fast_tanh(s), &out_r[rowA]);
  }
}

extern "C" void kernel_launch(void* const* d_in, const int* in_sizes, int n_in,
                              void* d_out, int out_size, void* d_ws, size_t ws_size,
                              hipStream_t stream) {
  const float* prev_h   = (const float*)d_in[0];
  const float* prev_c   = (const float*)d_in[1];
  const float* action   = (const float*)d_in[2];
  const float* dynamics = (const float*)d_in[3];
  const float* W1 = (const float*)d_in[4];
  const float* b1 = (const float*)d_in[5];
  const float* W2 = (const float*)d_in[6];
  const float* b2 = (const float*)d_in[7];
  const float* Wr = (const float*)d_in[8];
  const float* br = (const float*)d_in[9];
  short* wsw = (short*)d_ws;   // needs 120,832 bytes

  float* out_h = (float*)d_out;
  float* out_c = out_h + (size_t)65536 * 256;
  float* out_r = out_c + (size_t)65536 * 256;

  prep_weights<<<236, 256, 0, stream>>>(W1, W2, Wr, wsw);
  fclstm_main<<<2048, 256, 0, stream>>>(prev_h, prev_c, action, dynamics,
                                        b1, b2, Wr, br, wsw, out_h, out_c, out_r);
}

// Round 6
// 108.679 us; speedup vs baseline: 1.3058x; 1.3058x over previous
//
#include <hip/hip_runtime.h>
#include <hip/hip_bf16.h>

typedef float f32x4 __attribute__((ext_vector_type(4)));
typedef short bf16x8 __attribute__((ext_vector_type(8)));
typedef float float4v __attribute__((ext_vector_type(4)));

#define H1_STRIDE 40    // shorts; 32 + 8 pad
#define W1T_K 576
#define W2T_OFF (48 * 576)

__device__ __forceinline__ short f2bf(float f) {
  __bf16 b = (__bf16)f;
  return __builtin_bit_cast(short, b);
}
__device__ __forceinline__ uint pack2(float a, float b) {
  return (uint)(unsigned short)f2bf(a) | ((uint)(unsigned short)f2bf(b) << 16);
}
__device__ __forceinline__ float fast_sigmoid(float x) {
  return __builtin_amdgcn_rcpf(1.f + __expf(-x));
}
__device__ __forceinline__ float fast_tanh(float x) {
  float e = __expf(2.f * x);
  return 1.f - 2.f * __builtin_amdgcn_rcpf(e + 1.f);  // exact identity; saturates at +-1
}

// ---- prep: bf16 weight layouts in d_ws ----
// ws[0 .. 48*576)        : W1bT[n][k] = (n<32 ? W1[k][n] : n==32 ? Wr[k] : 0)   [K-contig]
// ws[48*576 .. +32*1024) : W2T[n][k] = W2[k][n]                                  [K-contig]
__global__ __launch_bounds__(256) void prep_weights(
    const float* __restrict__ W1, const float* __restrict__ W2,
    const float* __restrict__ Wr, short* __restrict__ ws)
{
  int i = blockIdx.x * 256 + threadIdx.x;
  if (i < 48 * 576) {
    int n = i / 576;
    int k = i - n * 576;
    float v = 0.f;
    if (n < 32) v = W1[k * 32 + n];
    else if (n == 32) v = Wr[k];
    ws[i] = f2bf(v);
  } else {
    int j = i - 48 * 576;
    if (j < 32 * 1024) {
      int n = j >> 5;
      int k = j & 31;
      ws[W2T_OFF + j] = f2bf(W2[k * 1024 + n]);
    }
  }
}

// Wave-PAIR decomposition: block = 4 waves = 2 pairs, 32 rows/block, grid 2048.
//   wave ks=0: fc1 k-steps 0..8,  fc2 col-tiles 0..7
//   wave ks=1: fc1 k-steps 9..17, fc2 col-tiles 8..15
// fc1 partials exchanged via LDS with raw lgkmcnt+s_barrier (no vmcnt drain ->
// prev_c prefetch stays in flight across the barrier).
// launch_bounds(256,6): 84-VGPR cap -- fits the ~70-reg demand WITHOUT spill
// (r5's (256,8)=64-cap spilled: +128MB scratch writes). 6 waves/SIMD = 75% occ.
__global__ __launch_bounds__(256, 6) void fclstm_main(
    const float* __restrict__ prev_h, const float* __restrict__ prev_c,
    const float* __restrict__ action, const float* __restrict__ dynamics,
    const float* __restrict__ b1, const float* __restrict__ b2,
    const float* __restrict__ Wr, const float* __restrict__ br,
    const short* __restrict__ wsw,
    float* __restrict__ out_h, float* __restrict__ out_c, float* __restrict__ out_r)
{
  __shared__ f32x4 accx[4][2][64];         //  8,192 B : fc1 acc0/acc1 exchange (lane-major)
  __shared__ short h1T[4][16 * H1_STRIDE]; //  5,120 B : per-wave h1 transpose buffer
  __shared__ float rlds[2][16];            //    128 B : reward partial (ks=1 -> ks=0)

  const int t    = threadIdx.x;
  const int wid  = t >> 6;
  const int lane = t & 63;
  const int lg   = lane >> 4;
  const int ln   = lane & 15;
  const int p    = wid >> 1;      // pair index 0/1
  const int ks   = wid & 1;       // k-half / col-half
  const int r0   = blockIdx.x * 32;
  const int m0   = p << 4;
  const int rowA = r0 + m0 + ln;  // THE batch row this lane owns
  const int kb   = 8 * lg;

  // ---- prev_c preload, first 4 of this wave's 8 col-tiles (hides under fc1)
  const float* pcp = prev_c + (size_t)rowA * 256 + ks * 128 + 4 * lg;
  float4v pcA[4], pcB[4];
  #pragma unroll
  for (int q = 0; q < 4; ++q) pcA[q] = *(const float4v*)(pcp + q * 16);

  // ---- fc1 partial: this wave's 9 k-steps ----
  f32x4 acc0 = {0.f,0.f,0.f,0.f};  // fc1 cols  0..15
  f32x4 acc1 = {0.f,0.f,0.f,0.f};  // fc1 cols 16..31
  f32x4 acc2 = {0.f,0.f,0.f,0.f};  // fc1 cols 32..47 (col 32 = x . Wr[0:576] partial)

  const float* dynp = dynamics + rowA * 256 + kb;
  const float* actp = action   + rowA * 64  + kb;
  const float* hp   = prev_h   + rowA * 256 + kb;
  const short* w1f  = wsw + ln * W1T_K + kb;

  auto fc1_step = [&](int j, const float* src) {
    float4v v0 = *(const float4v*)src;
    float4v v1 = *(const float4v*)(src + 4);
    bf16x8 a;
    a[0] = f2bf(v0.x); a[1] = f2bf(v0.y); a[2] = f2bf(v0.z); a[3] = f2bf(v0.w);
    a[4] = f2bf(v1.x); a[5] = f2bf(v1.y); a[6] = f2bf(v1.z); a[7] = f2bf(v1.w);
    bf16x8 bA = *(const bf16x8*)(w1f + 32 * j);
    bf16x8 bB = *(const bf16x8*)(w1f + 16 * W1T_K + 32 * j);
    bf16x8 bC = *(const bf16x8*)(w1f + 32 * W1T_K + 32 * j);
    acc0 = __builtin_amdgcn_mfma_f32_16x16x32_bf16(bA, a, acc0, 0, 0, 0);
    acc1 = __builtin_amdgcn_mfma_f32_16x16x32_bf16(bB, a, acc1, 0, 0, 0);
    acc2 = __builtin_amdgcn_mfma_f32_16x16x32_bf16(bC, a, acc2, 0, 0, 0);
  };

  if (ks == 0) {
    #pragma unroll
    for (int j = 0; j < 9; ++j)
      fc1_step(j, (j < 8) ? dynp + 32 * j : actp + 32 * j - 256);
  } else {
    #pragma unroll
    for (int j = 9; j < 18; ++j)
      fc1_step(j, (j < 10) ? actp + 32 * j - 256 : hp + 32 * j - 320);
  }

  // ---- exchange fc1 acc0/acc1 with the partner wave (raw barrier: no vmcnt drain)
  accx[wid][0][lane] = acc0;
  accx[wid][1][lane] = acc1;
  asm volatile("s_waitcnt lgkmcnt(0)" ::: "memory");
  __builtin_amdgcn_s_barrier();
  __builtin_amdgcn_sched_barrier(0);
  {
    const int pw = wid ^ 1;
    acc0 += accx[pw][0][lane];
    acc1 += accx[pw][1][lane];
  }

  // prev_c batch 1 (this wave's tiles 4..7) — issue now, hides under pack+fc2 start
  #pragma unroll
  for (int q = 0; q < 4; ++q) pcB[q] = *(const float4v*)(pcp + 64 + q * 16);

  // ---- h1 = tanh(.+b1); wave-local LDS transpose to build the fc2 B-frag
  {
    float4v b1lo = *(const float4v*)&b1[4 * lg];
    float4v b1hi = *(const float4v*)&b1[16 + 4 * lg];
    uint2 wlo, whi;
    wlo.x = pack2(fast_tanh(acc0[0] + b1lo.x), fast_tanh(acc0[1] + b1lo.y));
    wlo.y = pack2(fast_tanh(acc0[2] + b1lo.z), fast_tanh(acc0[3] + b1lo.w));
    whi.x = pack2(fast_tanh(acc1[0] + b1hi.x), fast_tanh(acc1[1] + b1hi.y));
    whi.y = pack2(fast_tanh(acc1[2] + b1hi.z), fast_tanh(acc1[3] + b1hi.w));
    short* hrow = &h1T[wid][ln * H1_STRIDE];
    *(uint2*)(hrow + 4 * lg)      = wlo;
    *(uint2*)(hrow + 16 + 4 * lg) = whi;
  }
  asm volatile("s_waitcnt lgkmcnt(0)" ::: "memory");
  __builtin_amdgcn_sched_barrier(0);
  bf16x8 af2 = *(const bf16x8*)(&h1T[wid][ln * H1_STRIDE] + 8 * lg);

  // ---- fc2 + LSTM elementwise + reward: this wave's 8 col-tiles ----
  float racc = 0.f;
  const float br0 = br[0];
  const short* w2t = wsw + W2T_OFF;
  const size_t orow = (size_t)rowA * 256;

  auto fc2_tile = [&](int nt, float4v pc) {
    const int c4 = nt * 16 + 4 * lg;                      // 4 consecutive out cols
    const short* aw = w2t + (nt * 16 + ln) * 32 + 8 * lg; // W2T rows as A-operand
    bf16x8 wi = *(const bf16x8*)(aw);
    bf16x8 wf = *(const bf16x8*)(aw + 256 * 32);
    bf16x8 wc = *(const bf16x8*)(aw + 512 * 32);
    bf16x8 wo = *(const bf16x8*)(aw + 768 * 32);
    f32x4 gi = {0.f,0.f,0.f,0.f}, gf = {0.f,0.f,0.f,0.f};
    f32x4 gc = {0.f,0.f,0.f,0.f}, go = {0.f,0.f,0.f,0.f};
    gi = __builtin_amdgcn_mfma_f32_16x16x32_bf16(wi, af2, gi, 0, 0, 0);
    gf = __builtin_amdgcn_mfma_f32_16x16x32_bf16(wf, af2, gf, 0, 0, 0);
    gc = __builtin_amdgcn_mfma_f32_16x16x32_bf16(wc, af2, gc, 0, 0, 0);
    go = __builtin_amdgcn_mfma_f32_16x16x32_bf16(wo, af2, go, 0, 0, 0);
    float4v b2i = *(const float4v*)&b2[c4];
    float4v b2f = *(const float4v*)&b2[256 + c4];
    float4v b2c = *(const float4v*)&b2[512 + c4];
    float4v b2o = *(const float4v*)&b2[768 + c4];
    float4v wrv = *(const float4v*)&Wr[576 + c4];
    float4v nh, nc2;
    #pragma unroll
    for (int r = 0; r < 4; ++r) {
      float iv  = fast_sigmoid(gi[r] + b2i[r]);
      float fv  = fast_sigmoid(gf[r] + b2f[r]);
      float cv  = fast_tanh(gc[r] + b2c[r]);
      float ov  = fast_sigmoid(go[r] + b2o[r]);
      float ncv = fv * pc[r] + iv * cv;
      float nhv = ov * fast_tanh(ncv);
      nh[r]  = nhv;
      nc2[r] = ncv;
      racc += nhv * wrv[r];
    }
    __builtin_nontemporal_store(nh,  (float4v*)(out_h + orow + c4));
    __builtin_nontemporal_store(nc2, (float4v*)(out_c + orow + c4));
  };

  #pragma unroll
  for (int q = 0; q < 4; ++q) fc2_tile(ks * 8 + q, pcA[q]);
  #pragma unroll
  for (int q = 0; q < 4; ++q) fc2_tile(ks * 8 + 4 + q, pcB[q]);

  // ---- reward: combine lg groups, then the two waves of the pair.
  // acc2[0] (fc1 col 32 = this k-half's x.Wr partial) is valid on lg==0 lanes.
  racc += __shfl_xor(racc, 16, 64);
  racc += __shfl_xor(racc, 32, 64);
  if (ks == 1 && lane < 16) rlds[p][lane] = racc + acc2[0];
  asm volatile("s_waitcnt lgkmcnt(0)" ::: "memory");
  __builtin_amdgcn_s_barrier();
  __builtin_amdgcn_sched_barrier(0);
  if (ks == 0 && lg == 0) {
    float s = acc2[0] + racc + rlds[p][ln] + br0;
    __builtin_nontemporal_store(fast_tanh(s), &out_r[rowA]);
  }
}

extern "C" void kernel_launch(void* const* d_in, const int* in_sizes, int n_in,
                              void* d_out, int out_size, void* d_ws, size_t ws_size,
                              hipStream_t stream) {
  const float* prev_h   = (const float*)d_in[0];
  const float* prev_c   = (const float*)d_in[1];
  const float* action   = (const float*)d_in[2];
  const float* dynamics = (const float*)d_in[3];
  const float* W1 = (const float*)d_in[4];
  const float* b1 = (const float*)d_in[5];
  const float* W2 = (const float*)d_in[6];
  const float* b2 = (const float*)d_in[7];
  const float* Wr = (const float*)d_in[8];
  const float* br = (const float*)d_in[9];
  short* wsw = (short*)d_ws;   // needs 120,832 bytes

  float* out_h = (float*)d_out;
  float* out_c = out_h + (size_t)65536 * 256;
  float* out_r = out_c + (size_t)65536 * 256;

  prep_weights<<<236, 256, 0, stream>>>(W1, W2, Wr, wsw);
  fclstm_main<<<2048, 256, 0, stream>>>(prev_h, prev_c, action, dynamics,
                                        b1, b2, Wr, br, wsw, out_h, out_c, out_r);
}

// Round 7
// 101.520 us; speedup vs baseline: 1.3979x; 1.0705x over previous
//
#include <hip/hip_runtime.h>
#include <hip/hip_bf16.h>

typedef float f32x4 __attribute__((ext_vector_type(4)));
typedef short bf16x8 __attribute__((ext_vector_type(8)));
typedef float float4v __attribute__((ext_vector_type(4)));

#define W1T_K 576
#define W2T_OFF (48 * 576)
#define H1_OFF (W2T_OFF + 32 * 1024)   // 60416 shorts = 120,832 B

__device__ __forceinline__ short f2bf(float f) {
  __bf16 b = (__bf16)f;
  return __builtin_bit_cast(short, b);
}
__device__ __forceinline__ uint pack2(float a, float b) {
  return (uint)(unsigned short)f2bf(a) | ((uint)(unsigned short)f2bf(b) << 16);
}
__device__ __forceinline__ float fast_sigmoid(float x) {
  return __builtin_amdgcn_rcpf(1.f + __expf(-x));
}
__device__ __forceinline__ float fast_tanh(float x) {
  float e = __expf(2.f * x);
  return 1.f - 2.f * __builtin_amdgcn_rcpf(e + 1.f);  // exact identity; saturates at +-1
}

// ---- prep: bf16 weight layouts in d_ws ----
// ws[0 .. 48*576)        : W1bT[n][k] = (n<32 ? W1[k][n] : n==32 ? Wr[k] : 0)
// ws[W2T_OFF .. +32*1024): W2T[n][k] = W2[k][n]
__global__ __launch_bounds__(256) void prep_weights(
    const float* __restrict__ W1, const float* __restrict__ W2,
    const float* __restrict__ Wr, short* __restrict__ ws)
{
  int i = blockIdx.x * 256 + threadIdx.x;
  if (i < 48 * 576) {
    int n = i / 576;
    int k = i - n * 576;
    float v = 0.f;
    if (n < 32) v = W1[k * 32 + n];
    else if (n == 32) v = Wr[k];
    ws[i] = f2bf(v);
  } else {
    int j = i - 48 * 576;
    if (j < 32 * 1024) {
      int n = j >> 5;
      int k = j & 31;
      ws[W2T_OFF + j] = f2bf(W2[k * 1024 + n]);
    }
  }
}

// ---- K1: h1 = tanh(X@W1+b1) [bf16], rdot = X.Wr[0:576] [f32] ----
// Transposed MFMA (W=A, X=B): lane ln owns batch row, 4lg+reg = h1 col.
// No LDS, no barriers, no mid-kernel HBM dependency.
__global__ __launch_bounds__(256, 8) void fc1_kernel(
    const float* __restrict__ prev_h, const float* __restrict__ action,
    const float* __restrict__ dynamics, const float* __restrict__ b1,
    const short* __restrict__ wsw, short* __restrict__ h1out,
    float* __restrict__ rdot)
{
  const int t = threadIdx.x;
  const int wid = t >> 6, lane = t & 63, lg = lane >> 4, ln = lane & 15;
  const int rowA = blockIdx.x * 64 + (wid << 4) + ln;
  const int kb = 8 * lg;

  f32x4 acc0 = {0.f,0.f,0.f,0.f};  // h1 cols  0..15
  f32x4 acc1 = {0.f,0.f,0.f,0.f};  // h1 cols 16..31
  f32x4 acc2 = {0.f,0.f,0.f,0.f};  // col 32 = x . Wr[0:576]

  const float* dynp = dynamics + rowA * 256 + kb;
  const float* actp = action   + rowA * 64  + kb;
  const float* hp   = prev_h   + rowA * 256 + kb;
  const short* w1f  = wsw + ln * W1T_K + kb;

  #pragma unroll
  for (int j = 0; j < 18; ++j) {
    const float* src = (j < 8) ? (dynp + 32 * j)
                     : (j < 10) ? (actp + 32 * j - 256)
                                : (hp + 32 * j - 320);
    float4v v0 = *(const float4v*)src;
    float4v v1 = *(const float4v*)(src + 4);
    bf16x8 a;
    a[0] = f2bf(v0.x); a[1] = f2bf(v0.y); a[2] = f2bf(v0.z); a[3] = f2bf(v0.w);
    a[4] = f2bf(v1.x); a[5] = f2bf(v1.y); a[6] = f2bf(v1.z); a[7] = f2bf(v1.w);
    bf16x8 bA = *(const bf16x8*)(w1f + 32 * j);
    bf16x8 bB = *(const bf16x8*)(w1f + 16 * W1T_K + 32 * j);
    bf16x8 bC = *(const bf16x8*)(w1f + 32 * W1T_K + 32 * j);
    acc0 = __builtin_amdgcn_mfma_f32_16x16x32_bf16(bA, a, acc0, 0, 0, 0);
    acc1 = __builtin_amdgcn_mfma_f32_16x16x32_bf16(bB, a, acc1, 0, 0, 0);
    acc2 = __builtin_amdgcn_mfma_f32_16x16x32_bf16(bC, a, acc2, 0, 0, 0);
  }

  // h1 row-major [B,32] bf16: lane writes cols 4lg..+3 and 16+4lg..+3 of its row
  float4v b1lo = *(const float4v*)&b1[4 * lg];
  float4v b1hi = *(const float4v*)&b1[16 + 4 * lg];
  uint2 wlo, whi;
  wlo.x = pack2(fast_tanh(acc0[0] + b1lo.x), fast_tanh(acc0[1] + b1lo.y));
  wlo.y = pack2(fast_tanh(acc0[2] + b1lo.z), fast_tanh(acc0[3] + b1lo.w));
  whi.x = pack2(fast_tanh(acc1[0] + b1hi.x), fast_tanh(acc1[1] + b1hi.y));
  whi.y = pack2(fast_tanh(acc1[2] + b1hi.z), fast_tanh(acc1[3] + b1hi.w));
  *(uint2*)&h1out[rowA * 32 + 4 * lg]      = wlo;   // byte off 64*row+8lg, 8B-aligned
  *(uint2*)&h1out[rowA * 32 + 16 + 4 * lg] = whi;
  if (lg == 0) rdot[rowA] = acc2[0];                // normal store: re-read by K2
}

// ---- K2: gates = h1@W2+b2, LSTM update, reward ----
// Wave-pair col-split (ks=0: cols 0..127, ks=1: cols 128..255) -- cols are
// independent, so NO mid-kernel barrier. h1-frag + all 8 prev_c tiles issued
// at entry (independent chains). Reward pair-combine at end via raw barrier.
__global__ __launch_bounds__(256, 6) void fc2_kernel(
    const float* __restrict__ prev_c, const float* __restrict__ b2,
    const float* __restrict__ Wr, const float* __restrict__ br,
    const short* __restrict__ wsw, const short* __restrict__ h1in,
    const float* __restrict__ rdot,
    float* __restrict__ out_h, float* __restrict__ out_c, float* __restrict__ out_r)
{
  __shared__ float rlds[2][16];

  const int t = threadIdx.x;
  const int wid = t >> 6, lane = t & 63, lg = lane >> 4, ln = lane & 15;
  const int p = wid >> 1, ks = wid & 1;
  const int rowA = blockIdx.x * 32 + (p << 4) + ln;

  // h1 fragment first (gates the MFMAs), then prev_c (gates only the epilogue)
  bf16x8 af2 = *(const bf16x8*)&h1in[rowA * 32 + 8 * lg];

  const float* pcp = prev_c + (size_t)rowA * 256 + ks * 128 + 4 * lg;
  float4v pcA[4], pcB[4];
  #pragma unroll
  for (int q = 0; q < 4; ++q) pcA[q] = *(const float4v*)(pcp + q * 16);
  #pragma unroll
  for (int q = 0; q < 4; ++q) pcB[q] = *(const float4v*)(pcp + 64 + q * 16);

  float racc = 0.f;
  const float br0 = br[0];
  const short* w2t = wsw + W2T_OFF;
  const size_t orow = (size_t)rowA * 256;

  auto fc2_tile = [&](int nt, float4v pc) {
    const int c4 = nt * 16 + 4 * lg;                      // 4 consecutive out cols
    const short* aw = w2t + (nt * 16 + ln) * 32 + 8 * lg; // W2T rows as A-operand
    bf16x8 wi = *(const bf16x8*)(aw);
    bf16x8 wf = *(const bf16x8*)(aw + 256 * 32);
    bf16x8 wc = *(const bf16x8*)(aw + 512 * 32);
    bf16x8 wo = *(const bf16x8*)(aw + 768 * 32);
    f32x4 gi = {0.f,0.f,0.f,0.f}, gf = {0.f,0.f,0.f,0.f};
    f32x4 gc = {0.f,0.f,0.f,0.f}, go = {0.f,0.f,0.f,0.f};
    gi = __builtin_amdgcn_mfma_f32_16x16x32_bf16(wi, af2, gi, 0, 0, 0);
    gf = __builtin_amdgcn_mfma_f32_16x16x32_bf16(wf, af2, gf, 0, 0, 0);
    gc = __builtin_amdgcn_mfma_f32_16x16x32_bf16(wc, af2, gc, 0, 0, 0);
    go = __builtin_amdgcn_mfma_f32_16x16x32_bf16(wo, af2, go, 0, 0, 0);
    float4v b2i = *(const float4v*)&b2[c4];
    float4v b2f = *(const float4v*)&b2[256 + c4];
    float4v b2c = *(const float4v*)&b2[512 + c4];
    float4v b2o = *(const float4v*)&b2[768 + c4];
    float4v wrv = *(const float4v*)&Wr[576 + c4];
    float4v nh, nc2;
    #pragma unroll
    for (int r = 0; r < 4; ++r) {
      float iv  = fast_sigmoid(gi[r] + b2i[r]);
      float fv  = fast_sigmoid(gf[r] + b2f[r]);
      float cv  = fast_tanh(gc[r] + b2c[r]);
      float ov  = fast_sigmoid(go[r] + b2o[r]);
      float ncv = fv * pc[r] + iv * cv;
      float nhv = ov * fast_tanh(ncv);
      nh[r]  = nhv;
      nc2[r] = ncv;
      racc += nhv * wrv[r];
    }
    __builtin_nontemporal_store(nh,  (float4v*)(out_h + orow + c4));
    __builtin_nontemporal_store(nc2, (float4v*)(out_c + orow + c4));
  };

  #pragma unroll
  for (int q = 0; q < 4; ++q) fc2_tile(ks * 8 + q, pcA[q]);
  #pragma unroll
  for (int q = 0; q < 4; ++q) fc2_tile(ks * 8 + 4 + q, pcB[q]);

  // reward: lane holds partial over its 4-col slots; fold lg groups, then pair.
  racc += __shfl_xor(racc, 16, 64);
  racc += __shfl_xor(racc, 32, 64);
  if (ks == 1 && lane < 16) rlds[p][lane] = racc;
  asm volatile("s_waitcnt lgkmcnt(0)" ::: "memory");
  __builtin_amdgcn_s_barrier();
  __builtin_amdgcn_sched_barrier(0);
  if (ks == 0 && lg == 0) {
    float s = rdot[rowA] + racc + rlds[p][ln] + br0;
    __builtin_nontemporal_store(fast_tanh(s), &out_r[rowA]);
  }
}

extern "C" void kernel_launch(void* const* d_in, const int* in_sizes, int n_in,
                              void* d_out, int out_size, void* d_ws, size_t ws_size,
                              hipStream_t stream) {
  const float* prev_h   = (const float*)d_in[0];
  const float* prev_c   = (const float*)d_in[1];
  const float* action   = (const float*)d_in[2];
  const float* dynamics = (const float*)d_in[3];
  const float* W1 = (const float*)d_in[4];
  const float* b1 = (const float*)d_in[5];
  const float* W2 = (const float*)d_in[6];
  const float* b2 = (const float*)d_in[7];
  const float* Wr = (const float*)d_in[8];
  const float* br = (const float*)d_in[9];

  short* wsw   = (short*)d_ws;
  short* h1buf = wsw + H1_OFF;                       // [B,32] bf16 = 4 MB
  float* rdot  = (float*)(h1buf + (size_t)65536 * 32); // [B] f32 = 256 KB
  // total ws use: 120,832 + 4,194,304*2 + 262,144 = ~8.8 MB

  float* out_h = (float*)d_out;
  float* out_c = out_h + (size_t)65536 * 256;
  float* out_r = out_c + (size_t)65536 * 256;

  prep_weights<<<236, 256, 0, stream>>>(W1, W2, Wr, wsw);
  fc1_kernel<<<1024, 256, 0, stream>>>(prev_h, action, dynamics, b1, wsw, h1buf, rdot);
  fc2_kernel<<<2048, 256, 0, stream>>>(prev_c, b2, Wr, br, wsw, h1buf, rdot,
                                       out_h, out_c, out_r);
}

// Round 8
// 77.763 us; speedup vs baseline: 1.8249x; 1.3055x over previous
//
#include <hip/hip_runtime.h>
#include <hip/hip_bf16.h>

typedef float f32x4 __attribute__((ext_vector_type(4)));
typedef short bf16x8 __attribute__((ext_vector_type(8)));
typedef float float4v __attribute__((ext_vector_type(4)));

#define W2T_OFF (48 * 576)
#define H1_OFF (W2T_OFF + 32 * 1024)   // shorts

__device__ __forceinline__ short f2bf(float f) {
  __bf16 b = (__bf16)f;
  return __builtin_bit_cast(short, b);
}
__device__ __forceinline__ uint pack2(float a, float b) {
  return (uint)(unsigned short)f2bf(a) | ((uint)(unsigned short)f2bf(b) << 16);
}
__device__ __forceinline__ float fast_sigmoid(float x) {
  return __builtin_amdgcn_rcpf(1.f + __expf(-x));
}
__device__ __forceinline__ float fast_tanh(float x) {
  float e = __expf(2.f * x);
  return 1.f - 2.f * __builtin_amdgcn_rcpf(e + 1.f);
}
// volatile asm load: compiler CANNOT sink this past its source position.
__device__ __forceinline__ float4v ld16(const float* p) {
  float4v r;
  asm volatile("global_load_dwordx4 %0, %1, off" : "=v"(r) : "v"(p));
  return r;
}

// ---- prep ----
// W1bT region: row n (0..47) of 576 shorts, XOR-swizzled per 16B unit:
//   phys(n,k) = n*576 + (((k>>3) ^ (n&7))<<3) + (k&7)
//   (n<32: W1 col n; n==32: Wr[0:576]; else 0)
// W2T region (linear): W2T[n][k] = W2[k][n]
__global__ __launch_bounds__(256) void prep_weights(
    const float* __restrict__ W1, const float* __restrict__ W2,
    const float* __restrict__ Wr, short* __restrict__ ws)
{
  int i = blockIdx.x * 256 + threadIdx.x;
  if (i < 48 * 576) {
    int n = i / 576;
    int k = i - n * 576;
    float v = 0.f;
    if (n < 32) v = W1[k * 32 + n];
    else if (n == 32) v = Wr[k];
    int phys = n * 576 + ((((k >> 3) ^ (n & 7)) << 3) | (k & 7));
    ws[phys] = f2bf(v);
  } else {
    int j = i - 48 * 576;
    if (j < 32 * 1024) {
      int n = j >> 5;
      int k = j & 31;
      ws[W2T_OFF + j] = f2bf(W2[k * 1024 + n]);
    }
  }
}

// ---- K1: h1 = tanh(X@W1+b1) bf16, rdot = X.Wr[0:576] f32 ----
// 512 thr / 128 rows / grid 512. Weights in LDS (lgkm domain) so vmcnt is
// owned exclusively by the hand-pipelined asm X loads (depth 6 = 12 dwordx4
// = 768B/wave in flight; x16 waves/CU = 12KB/CU > Little's-law 9.2KB).
__global__ __launch_bounds__(512, 4) void fc1_kernel(
    const float* __restrict__ prev_h, const float* __restrict__ action,
    const float* __restrict__ dynamics, const float* __restrict__ b1,
    const short* __restrict__ wsw, short* __restrict__ h1out,
    float* __restrict__ rdot)
{
  __shared__ short wlds[48 * 576];   // 55,296 B

  const int t = threadIdx.x;
  // stage all fc1 weights once: 7 x 8KB memcpy rounds, direct-to-LDS
  #pragma unroll
  for (int i = 0; i < 7; ++i) {
    int off = i * 8192 + t * 16;     // bytes
    if (off < 55296) {
      __builtin_amdgcn_global_load_lds(
          (const __attribute__((address_space(1))) void*)((const char*)wsw + off),
          (__attribute__((address_space(3))) void*)((char*)wlds + off), 16, 0, 0);
    }
  }
  __syncthreads();   // drains staging vmcnt; X pipeline starts clean after this

  const int wid = t >> 6, lane = t & 63, lg = lane >> 4, ln = lane & 15;
  const int lnx = ln & 7;
  const int rowA = blockIdx.x * 128 + wid * 16 + ln;
  const int kb = 8 * lg;

  const float* dynp = dynamics + rowA * 256 + kb;
  const float* actp = action   + rowA * 64  + kb;
  const float* hp   = prev_h   + rowA * 256 + kb;

  auto asrc = [&](int j) -> const float* {
    return (j < 8) ? (dynp + 32 * j)
         : (j < 10) ? (actp + 32 * j - 256)
                    : (hp + 32 * j - 320);
  };

  f32x4 acc0 = {0.f,0.f,0.f,0.f};
  f32x4 acc1 = {0.f,0.f,0.f,0.f};
  f32x4 acc2 = {0.f,0.f,0.f,0.f};

  float4v ab[6][2];
  #pragma unroll
  for (int j = 0; j < 6; ++j) {      // prologue: 12 loads in flight
    const float* p = asrc(j);
    ab[j][0] = ld16(p);
    ab[j][1] = ld16(p + 4);
  }

#define FC1_STEP(J, S, IMM)                                                  \
  {                                                                          \
    asm volatile("s_waitcnt vmcnt(" #IMM ")");                               \
    __builtin_amdgcn_sched_barrier(0);                                       \
    float4v v0 = ab[S][0], v1 = ab[S][1];                                    \
    bf16x8 a;                                                                \
    a[0]=f2bf(v0.x); a[1]=f2bf(v0.y); a[2]=f2bf(v0.z); a[3]=f2bf(v0.w);      \
    a[4]=f2bf(v1.x); a[5]=f2bf(v1.y); a[6]=f2bf(v1.z); a[7]=f2bf(v1.w);      \
    const int uo = ((4 * (J) + lg) ^ lnx) << 3;                              \
    bf16x8 bA = *(const bf16x8*)&wlds[ln * 576 + uo];                        \
    bf16x8 bB = *(const bf16x8*)&wlds[(ln + 16) * 576 + uo];                 \
    bf16x8 bC = *(const bf16x8*)&wlds[(ln + 32) * 576 + uo];                 \
    acc0 = __builtin_amdgcn_mfma_f32_16x16x32_bf16(bA, a, acc0, 0, 0, 0);    \
    acc1 = __builtin_amdgcn_mfma_f32_16x16x32_bf16(bB, a, acc1, 0, 0, 0);    \
    acc2 = __builtin_amdgcn_mfma_f32_16x16x32_bf16(bC, a, acc2, 0, 0, 0);    \
    if ((J) + 6 < 18) {                                                      \
      const float* np = asrc((J) + 6);                                       \
      ab[S][0] = ld16(np);                                                   \
      ab[S][1] = ld16(np + 4);                                               \
    }                                                                        \
  }

  FC1_STEP(0,0,10)  FC1_STEP(1,1,10)  FC1_STEP(2,2,10)  FC1_STEP(3,3,10)
  FC1_STEP(4,4,10)  FC1_STEP(5,5,10)  FC1_STEP(6,0,10)  FC1_STEP(7,1,10)
  FC1_STEP(8,2,10)  FC1_STEP(9,3,10)  FC1_STEP(10,4,10) FC1_STEP(11,5,10)
  FC1_STEP(12,0,10) FC1_STEP(13,1,8)  FC1_STEP(14,2,6)  FC1_STEP(15,3,4)
  FC1_STEP(16,4,2)  FC1_STEP(17,5,0)
#undef FC1_STEP

  // epilogue: tanh + bias, pack bf16, store h1 row + rdot
  float4v b1lo = *(const float4v*)&b1[4 * lg];
  float4v b1hi = *(const float4v*)&b1[16 + 4 * lg];
  uint2 wlo, whi;
  wlo.x = pack2(fast_tanh(acc0[0] + b1lo.x), fast_tanh(acc0[1] + b1lo.y));
  wlo.y = pack2(fast_tanh(acc0[2] + b1lo.z), fast_tanh(acc0[3] + b1lo.w));
  whi.x = pack2(fast_tanh(acc1[0] + b1hi.x), fast_tanh(acc1[1] + b1hi.y));
  whi.y = pack2(fast_tanh(acc1[2] + b1hi.z), fast_tanh(acc1[3] + b1hi.w));
  *(uint2*)&h1out[rowA * 32 + 4 * lg]      = wlo;
  *(uint2*)&h1out[rowA * 32 + 16 + 4 * lg] = whi;
  if (lg == 0) rdot[rowA] = acc2[0];
}

// ---- K2: gates = h1@W2+b2, LSTM update, reward ----
// 256 thr / 32 rows / grid 2048. prev_c (32KB contiguous) staged via
// global_load_lds with SOURCE-side XOR pre-swizzle (16B units: col^(row&7)),
// read back with the same XOR -> ~2-way banks instead of 16-way.
// Stores issued in adjacent-64B pairs so NT write-combine merges 128B lines.
__global__ __launch_bounds__(256, 6) void fc2_kernel(
    const float* __restrict__ prev_c, const float* __restrict__ b2,
    const float* __restrict__ Wr, const float* __restrict__ br,
    const short* __restrict__ wsw, const short* __restrict__ h1in,
    const float* __restrict__ rdot,
    float* __restrict__ out_h, float* __restrict__ out_c, float* __restrict__ out_r)
{
  __shared__ float pc_lds[32 * 256];   // 32 KB
  __shared__ float rlds[2][16];

  const int t = threadIdx.x;
  const int wid = t >> 6, lane = t & 63, lg = lane >> 4, ln = lane & 15;
  const int p = wid >> 1, ks = wid & 1;
  const int r0 = blockIdx.x * 32;
  const int rowA = r0 + p * 16 + ln;

  // h1 fragment (completes by the barrier)
  bf16x8 af2 = *(const bf16x8*)&h1in[rowA * 32 + 8 * lg];

  // stage prev_c rows r0..r0+31: linear LDS dest, pre-swizzled global source
  {
    const float* src = prev_c + (size_t)r0 * 256;
    #pragma unroll
    for (int i = 0; i < 8; ++i) {
      int u = i * 256 + t;                            // 16B unit in LDS
      int g = (u & ~63) | ((u & 63) ^ ((u >> 6) & 7)); // swizzled source unit
      __builtin_amdgcn_global_load_lds(
          (const __attribute__((address_space(1))) void*)(src + g * 4),
          (__attribute__((address_space(3))) void*)&pc_lds[u * 4], 16, 0, 0);
    }
  }
  __syncthreads();

  float racc = 0.f;
  const float br0 = br[0];
  const short* w2t = wsw + W2T_OFF;
  const size_t orow = (size_t)rowA * 256;
  const int lrow = (p * 16 + ln) * 64;   // this lane's LDS row base (16B units)
  const int lnx = ln & 7;

  auto fc2_tile = [&](int nt, float4v& nh, float4v& nc2) {
    const int c4 = nt * 16 + 4 * lg;
    const short* aw = w2t + (nt * 16 + ln) * 32 + 8 * lg;
    bf16x8 wi = *(const bf16x8*)(aw);
    bf16x8 wf = *(const bf16x8*)(aw + 256 * 32);
    bf16x8 wc = *(const bf16x8*)(aw + 512 * 32);
    bf16x8 wo = *(const bf16x8*)(aw + 768 * 32);
    f32x4 gi = {0.f,0.f,0.f,0.f}, gf = {0.f,0.f,0.f,0.f};
    f32x4 gc = {0.f,0.f,0.f,0.f}, go = {0.f,0.f,0.f,0.f};
    gi = __builtin_amdgcn_mfma_f32_16x16x32_bf16(wi, af2, gi, 0, 0, 0);
    gf = __builtin_amdgcn_mfma_f32_16x16x32_bf16(wf, af2, gf, 0, 0, 0);
    gc = __builtin_amdgcn_mfma_f32_16x16x32_bf16(wc, af2, gc, 0, 0, 0);
    go = __builtin_amdgcn_mfma_f32_16x16x32_bf16(wo, af2, go, 0, 0, 0);
    float4v pc = *(const float4v*)&pc_lds[(lrow + ((nt * 4 + lg) ^ lnx)) * 4];
    float4v b2i = *(const float4v*)&b2[c4];
    float4v b2f = *(const float4v*)&b2[256 + c4];
    float4v b2c = *(const float4v*)&b2[512 + c4];
    float4v b2o = *(const float4v*)&b2[768 + c4];
    float4v wrv = *(const float4v*)&Wr[576 + c4];
    #pragma unroll
    for (int r = 0; r < 4; ++r) {
      float iv  = fast_sigmoid(gi[r] + b2i[r]);
      float fv  = fast_sigmoid(gf[r] + b2f[r]);
      float cv  = fast_tanh(gc[r] + b2c[r]);
      float ov  = fast_sigmoid(go[r] + b2o[r]);
      float ncv = fv * pc[r] + iv * cv;
      float nhv = ov * fast_tanh(ncv);
      nh[r]  = nhv;
      nc2[r] = ncv;
      racc += nhv * wrv[r];
    }
  };

  #pragma unroll
  for (int qq = 0; qq < 4; ++qq) {
    const int nt0 = ks * 8 + 2 * qq;
    float4v nh0, nc0, nh1, nc1;
    fc2_tile(nt0,     nh0, nc0);
    fc2_tile(nt0 + 1, nh1, nc1);
    const size_t b0 = orow + nt0 * 16 + 4 * lg;
    __builtin_nontemporal_store(nh0, (float4v*)(out_h + b0));
    __builtin_nontemporal_store(nh1, (float4v*)(out_h + b0 + 16));
    __builtin_nontemporal_store(nc0, (float4v*)(out_c + b0));
    __builtin_nontemporal_store(nc1, (float4v*)(out_c + b0 + 16));
  }

  // reward: fold lg groups, then combine the wave pair via LDS
  racc += __shfl_xor(racc, 16, 64);
  racc += __shfl_xor(racc, 32, 64);
  if (ks == 1 && lane < 16) rlds[p][lane] = racc;
  asm volatile("s_waitcnt lgkmcnt(0)" ::: "memory");
  __builtin_amdgcn_s_barrier();
  __builtin_amdgcn_sched_barrier(0);
  if (ks == 0 && lg == 0) {
    float s = rdot[rowA] + racc + rlds[p][ln] + br0;
    __builtin_nontemporal_store(fast_tanh(s), &out_r[rowA]);
  }
}

extern "C" void kernel_launch(void* const* d_in, const int* in_sizes, int n_in,
                              void* d_out, int out_size, void* d_ws, size_t ws_size,
                              hipStream_t stream) {
  const float* prev_h   = (const float*)d_in[0];
  const float* prev_c   = (const float*)d_in[1];
  const float* action   = (const float*)d_in[2];
  const float* dynamics = (const float*)d_in[3];
  const float* W1 = (const float*)d_in[4];
  const float* b1 = (const float*)d_in[5];
  const float* W2 = (const float*)d_in[6];
  const float* b2 = (const float*)d_in[7];
  const float* Wr = (const float*)d_in[8];
  const float* br = (const float*)d_in[9];

  short* wsw   = (short*)d_ws;
  short* h1buf = wsw + H1_OFF;                          // [B,32] bf16 = 4 MB
  float* rdot  = (float*)(h1buf + (size_t)65536 * 32);  // [B] f32 = 256 KB

  float* out_h = (float*)d_out;
  float* out_c = out_h + (size_t)65536 * 256;
  float* out_r = out_c + (size_t)65536 * 256;

  prep_weights<<<236, 256, 0, stream>>>(W1, W2, Wr, wsw);
  fc1_kernel<<<512, 512, 0, stream>>>(prev_h, action, dynamics, b1, wsw, h1buf, rdot);
  fc2_kernel<<<2048, 256, 0, stream>>>(prev_c, b2, Wr, br, wsw, h1buf, rdot,
                                       out_h, out_c, out_r);
}